// Round 1
// baseline (1368.271 us; speedup 1.0000x reference)
//
#include <hip/hip_runtime.h>
#include <hip/hip_bf16.h>
#include <math.h>

#define N_NODES 50000
#define N_EDGES 800000
#define DIM 128
#define NH 4
#define DH 32

// ---------------- BN stats: per-column sum & sumsq ----------------
__global__ __launch_bounds__(256) void bn_stats_kernel(
    const float* __restrict__ x, int M, float* __restrict__ out /*[sum128, sq128]*/) {
  __shared__ float s_sum[DIM];
  __shared__ float s_sq[DIM];
  int t = threadIdx.x;  // 256
  if (t < DIM) { s_sum[t] = 0.f; s_sq[t] = 0.f; }
  __syncthreads();
  int c4 = (t & 31) * 4;   // column group (float4)
  int rg = t >> 5;         // row sub-group: 8 rows per iteration
  float sum0=0,sum1=0,sum2=0,sum3=0, sq0=0,sq1=0,sq2=0,sq3=0;
  for (long row = (long)blockIdx.x * 8 + rg; row < M; row += (long)gridDim.x * 8) {
    float4 v = *reinterpret_cast<const float4*>(x + row * DIM + c4);
    sum0 += v.x; sq0 += v.x * v.x;
    sum1 += v.y; sq1 += v.y * v.y;
    sum2 += v.z; sq2 += v.z * v.z;
    sum3 += v.w; sq3 += v.w * v.w;
  }
  atomicAdd(&s_sum[c4 + 0], sum0); atomicAdd(&s_sq[c4 + 0], sq0);
  atomicAdd(&s_sum[c4 + 1], sum1); atomicAdd(&s_sq[c4 + 1], sq1);
  atomicAdd(&s_sum[c4 + 2], sum2); atomicAdd(&s_sq[c4 + 2], sq2);
  atomicAdd(&s_sum[c4 + 3], sum3); atomicAdd(&s_sq[c4 + 3], sq3);
  __syncthreads();
  if (t < DIM) {
    atomicAdd(&out[t], s_sum[t]);
    atomicAdd(&out[DIM + t], s_sq[t]);
  }
}

// ---------------- finalize affine a,b from stats ----------------
__global__ __launch_bounds__(128) void finalize_ab_kernel(
    const float* __restrict__ stats, float M,
    const float* __restrict__ gamma, const float* __restrict__ beta,
    float* __restrict__ ab /*[a128, b128]*/) {
  int t = threadIdx.x;  // 128
  float mean = stats[t] / M;
  float var = stats[DIM + t] / M - mean * mean;
  float a = gamma[t] * rsqrtf(var + 1e-5f);
  ab[t] = a;
  ab[DIM + t] = beta[t] - mean * a;
}

// ---------------- fold BN affine into a 128x128 weight ----------------
__global__ __launch_bounds__(128) void fold_weight_kernel(
    const float* __restrict__ W, const float* __restrict__ ab,
    float* __restrict__ Wf, float* __restrict__ bias) {
  __shared__ float sa[DIM], sb[DIM];
  int d = threadIdx.x;  // 128
  sa[d] = ab[d];
  sb[d] = ab[DIM + d];
  __syncthreads();
  float acc = 0.f;
  for (int c = 0; c < DIM; ++c) {
    float wv = W[c * DIM + d];
    Wf[c * DIM + d] = sa[c] * wv;
    acc += sb[c] * wv;
  }
  bias[d] = acc;
}

// ---------------- QKV: 16 nodes per block ----------------
__global__ __launch_bounds__(128) void qkv_kernel(
    const float* __restrict__ nf,
    const float* __restrict__ Wq, const float* __restrict__ Wk, const float* __restrict__ Wv,
    const float* __restrict__ bq, const float* __restrict__ bk, const float* __restrict__ bv,
    float* __restrict__ Q, float* __restrict__ K, float* __restrict__ V) {
  __shared__ float rows[16][DIM];
  int t = threadIdx.x;  // 128
  int n0 = blockIdx.x * 16;
  for (int i = 0; i < 16; ++i) rows[i][t] = nf[(long)(n0 + i) * DIM + t];
  __syncthreads();
  float aq[16], ak[16], av[16];
  float bqv = bq[t], bkv = bk[t], bvv = bv[t];
#pragma unroll
  for (int i = 0; i < 16; ++i) { aq[i] = bqv; ak[i] = bkv; av[i] = bvv; }
  for (int c = 0; c < DIM; ++c) {
    float wq = Wq[c * DIM + t], wk = Wk[c * DIM + t], wv = Wv[c * DIM + t];
#pragma unroll
    for (int i = 0; i < 16; ++i) {
      float r = rows[i][c];
      aq[i] += r * wq; ak[i] += r * wk; av[i] += r * wv;
    }
  }
  for (int i = 0; i < 16; ++i) {
    long idx = (long)(n0 + i) * DIM + t;
    Q[idx] = aq[i]; K[idx] = ak[i]; V[idx] = av[i];
  }
}

// ---------------- edge attention: 16 edges per block ----------------
__global__ __launch_bounds__(128) void edge_kernel(
    const float* __restrict__ ef,
    const int* __restrict__ src, const int* __restrict__ dst,
    const float* __restrict__ WeF, const float* __restrict__ be,
    const float* __restrict__ Q, const float* __restrict__ K, const float* __restrict__ V,
    float* __restrict__ wV, float* __restrict__ z) {
  __shared__ float rows[16][DIM];
  __shared__ int s_src[16], s_dst[16];
  int t = threadIdx.x;  // 128
  long e0 = (long)blockIdx.x * 16;
  for (int i = 0; i < 16; ++i) rows[i][t] = ef[(e0 + i) * DIM + t];
  if (t < 16) { s_src[t] = src[e0 + t]; s_dst[t] = dst[e0 + t]; }
  __syncthreads();
  // proj_e for 16 edges (folded BN): pe[i] = sum_c rows[i][c]*WeF[c][t] + be[t]
  float pe[16];
  float bev = be[t];
#pragma unroll
  for (int i = 0; i < 16; ++i) pe[i] = bev;
  for (int c = 0; c < DIM; ++c) {
    float wv = WeF[c * DIM + t];
#pragma unroll
    for (int i = 0; i < 16; ++i) pe[i] += rows[i][c] * wv;
  }
  const float inv_s = 0.17677669529663687f;  // 1/sqrt(32)
  int h = t >> 5;  // head of this column
  for (int i = 0; i < 16; ++i) {
    int sn = s_src[i], dn = s_dst[i];
    float kv = K[(long)sn * DIM + t];
    float qv = Q[(long)dn * DIM + t];
    float sc = kv * qv * inv_s;
    sc = fminf(fmaxf(sc, -5.f), 5.f);
    sc *= pe[i];
    // reduce over the 32 lanes of this head group
    for (int m = 16; m >= 1; m >>= 1) sc += __shfl_xor(sc, m);
    float ssum = fminf(fmaxf(sc, -5.f), 5.f);
    float s = expf(ssum);
    float vv = V[(long)sn * DIM + t];
    atomicAdd(&wV[(long)dn * DIM + t], s * vv);
    if ((t & 31) == 0) atomicAdd(&z[dn * NH + h], s);
  }
}

// ---------------- attention out: h = wV/z @ O_w + O_b + residual; BN2 stats ----------------
__global__ __launch_bounds__(128) void attnout_kernel(
    const float* __restrict__ wV, const float* __restrict__ z,
    const float* __restrict__ Ow, const float* __restrict__ Ob,
    const float* __restrict__ h_in1,
    float* __restrict__ hres, float* __restrict__ stats2) {
  __shared__ float rows[16][DIM];
  int t = threadIdx.x;  // 128
  int n0 = blockIdx.x * 16;
  for (int i = 0; i < 16; ++i) {
    int n = n0 + i;
    float zz = z[n * NH + (t >> 5)];
    rows[i][t] = wV[(long)n * DIM + t] / (zz + 1e-6f);
  }
  __syncthreads();
  float acc[16];
  float ob = Ob[t];
#pragma unroll
  for (int i = 0; i < 16; ++i) acc[i] = ob;
  for (int c = 0; c < DIM; ++c) {
    float wv = Ow[c * DIM + t];
#pragma unroll
    for (int i = 0; i < 16; ++i) acc[i] += rows[i][c] * wv;
  }
  float lsum = 0.f, lsq = 0.f;
  for (int i = 0; i < 16; ++i) {
    long idx = (long)(n0 + i) * DIM + t;
    float hv = h_in1[idx] + acc[i];
    hres[idx] = hv;
    lsum += hv; lsq += hv * hv;
  }
  atomicAdd(&stats2[t], lsum);
  atomicAdd(&stats2[DIM + t], lsq);
}

// ---------------- MLP: 8 nodes per block, 256 threads ----------------
__global__ __launch_bounds__(256) void mlp_kernel(
    const float* hres, const float* __restrict__ ab2,
    const float* __restrict__ W1, const float* __restrict__ W2,
    float* out) {
  __shared__ float rows[8][DIM];
  __shared__ float mid[8][2 * DIM];
  int t = threadIdx.x;  // 256
  int n0 = blockIdx.x * 8;
  {
    int c = t & 127;
    int half = t >> 7;
    float a = ab2[c], b = ab2[DIM + c];
    for (int i = half; i < 8; i += 2) {
      float hv = hres[(long)(n0 + i) * DIM + c];
      rows[i][c] = a * hv + b;
    }
  }
  __syncthreads();
  // phase 1: mid = silu(rows @ W1)  (W1: [128][256])
  float acc[8];
#pragma unroll
  for (int i = 0; i < 8; ++i) acc[i] = 0.f;
  for (int c = 0; c < DIM; ++c) {
    float wv = W1[c * 2 * DIM + t];
#pragma unroll
    for (int i = 0; i < 8; ++i) acc[i] += rows[i][c] * wv;
  }
#pragma unroll
  for (int i = 0; i < 8; ++i) {
    float x = acc[i];
    mid[i][t] = x / (1.f + expf(-x));
  }
  __syncthreads();
  // phase 2: out = hres + mid @ W2  (W2: [256][128])
  int d = t & 127;
  int half = t >> 7;
  float acc2[4];
#pragma unroll
  for (int j = 0; j < 4; ++j) acc2[j] = 0.f;
  for (int k = 0; k < 2 * DIM; ++k) {
    float wv = W2[k * DIM + d];
#pragma unroll
    for (int j = 0; j < 4; ++j) acc2[j] += mid[half + j * 2][k] * wv;
  }
#pragma unroll
  for (int j = 0; j < 4; ++j) {
    int i = half + j * 2;
    long idx = (long)(n0 + i) * DIM + d;
    out[idx] = hres[idx] + acc2[j];
  }
}

extern "C" void kernel_launch(void* const* d_in, const int* in_sizes, int n_in,
                              void* d_out, int out_size, void* d_ws, size_t ws_size,
                              hipStream_t stream) {
  const float* node_feats = (const float*)d_in[0];
  const float* edge_feats = (const float*)d_in[1];
  const int* src = (const int*)d_in[2];
  const int* dst = (const int*)d_in[3];
  const float* Wq = (const float*)d_in[4];
  const float* Wk = (const float*)d_in[5];
  const float* Wv = (const float*)d_in[6];
  const float* We = (const float*)d_in[7];
  const float* Ow = (const float*)d_in[8];
  const float* Ob = (const float*)d_in[9];
  const float* g1n = (const float*)d_in[10];
  const float* b1n = (const float*)d_in[11];
  const float* g1e = (const float*)d_in[12];
  const float* b1e = (const float*)d_in[13];
  const float* g2 = (const float*)d_in[14];
  const float* b2 = (const float*)d_in[15];
  const float* W1 = (const float*)d_in[16];
  const float* W2 = (const float*)d_in[17];
  float* out = (float*)d_out;
  float* w = (float*)d_ws;

  float* stats_n = w + 0;
  float* stats_e = w + 256;
  float* stats_h = w + 512;
  float* ab_n = w + 768;
  float* ab_e = w + 1024;
  float* ab_2 = w + 1280;
  float* bq = w + 1536;
  float* bk = w + 1664;
  float* bv = w + 1792;
  float* be = w + 1920;
  float* WqF = w + 2048;
  float* WkF = w + 18432;
  float* WvF = w + 34816;
  float* WeF = w + 51200;
  float* Q = w + 67584;
  float* K = Q + (size_t)N_NODES * DIM;
  float* V = K + (size_t)N_NODES * DIM;
  float* wV = V + (size_t)N_NODES * DIM;
  float* z = wV + (size_t)N_NODES * DIM;

  // zero the accumulators (stats + scatter targets)
  hipMemsetAsync(w, 0, 768 * sizeof(float), stream);
  hipMemsetAsync(wV, 0, (size_t)(N_NODES * DIM + N_NODES * NH) * sizeof(float), stream);

  bn_stats_kernel<<<512, 256, 0, stream>>>(node_feats, N_NODES, stats_n);
  bn_stats_kernel<<<2048, 256, 0, stream>>>(edge_feats, N_EDGES, stats_e);
  finalize_ab_kernel<<<1, 128, 0, stream>>>(stats_n, (float)N_NODES, g1n, b1n, ab_n);
  finalize_ab_kernel<<<1, 128, 0, stream>>>(stats_e, (float)N_EDGES, g1e, b1e, ab_e);
  fold_weight_kernel<<<1, 128, 0, stream>>>(Wq, ab_n, WqF, bq);
  fold_weight_kernel<<<1, 128, 0, stream>>>(Wk, ab_n, WkF, bk);
  fold_weight_kernel<<<1, 128, 0, stream>>>(Wv, ab_n, WvF, bv);
  fold_weight_kernel<<<1, 128, 0, stream>>>(We, ab_e, WeF, be);
  qkv_kernel<<<N_NODES / 16, 128, 0, stream>>>(node_feats, WqF, WkF, WvF, bq, bk, bv, Q, K, V);
  edge_kernel<<<N_EDGES / 16, 128, 0, stream>>>(edge_feats, src, dst, WeF, be, Q, K, V, wV, z);
  attnout_kernel<<<N_NODES / 16, 128, 0, stream>>>(wV, z, Ow, Ob, node_feats, out, stats_h);
  finalize_ab_kernel<<<1, 128, 0, stream>>>(stats_h, (float)N_NODES, g2, b2, ab_2);
  mlp_kernel<<<N_NODES / 8, 256, 0, stream>>>(out, ab_2, W1, W2, out);
}

// Round 2
// 1168.136 us; speedup vs baseline: 1.1713x; 1.1713x over previous
//
#include <hip/hip_runtime.h>
#include <hip/hip_bf16.h>
#include <math.h>

#define N_NODES 50000
#define N_EDGES 800000
#define DIM 128
#define NH 4

typedef __attribute__((ext_vector_type(8))) short bf16x8;
typedef __attribute__((ext_vector_type(4))) float f32x4;

__device__ inline short f2bf(float f) {
  __hip_bfloat16 h = __float2bfloat16(f);
  return __builtin_bit_cast(short, h);
}

// ---------------- BN stats: per-column sum & sumsq ----------------
__global__ __launch_bounds__(256) void bn_stats_kernel(
    const float* __restrict__ x, int M, float* __restrict__ out /*[sum128, sq128]*/) {
  __shared__ float s_sum[DIM];
  __shared__ float s_sq[DIM];
  int t = threadIdx.x;  // 256
  if (t < DIM) { s_sum[t] = 0.f; s_sq[t] = 0.f; }
  __syncthreads();
  int c4 = (t & 31) * 4;   // column group (float4)
  int rg = t >> 5;         // row sub-group: 8 rows per iteration
  float sum0=0,sum1=0,sum2=0,sum3=0, sq0=0,sq1=0,sq2=0,sq3=0;
  for (long row = (long)blockIdx.x * 8 + rg; row < M; row += (long)gridDim.x * 8) {
    float4 v = *reinterpret_cast<const float4*>(x + row * DIM + c4);
    sum0 += v.x; sq0 += v.x * v.x;
    sum1 += v.y; sq1 += v.y * v.y;
    sum2 += v.z; sq2 += v.z * v.z;
    sum3 += v.w; sq3 += v.w * v.w;
  }
  atomicAdd(&s_sum[c4 + 0], sum0); atomicAdd(&s_sq[c4 + 0], sq0);
  atomicAdd(&s_sum[c4 + 1], sum1); atomicAdd(&s_sq[c4 + 1], sq1);
  atomicAdd(&s_sum[c4 + 2], sum2); atomicAdd(&s_sq[c4 + 2], sq2);
  atomicAdd(&s_sum[c4 + 3], sum3); atomicAdd(&s_sq[c4 + 3], sq3);
  __syncthreads();
  if (t < DIM) {
    atomicAdd(&out[t], s_sum[t]);
    atomicAdd(&out[DIM + t], s_sq[t]);
  }
}

// ---------------- finalize affine a,b from stats ----------------
__global__ __launch_bounds__(128) void finalize_ab_kernel(
    const float* __restrict__ stats, float M,
    const float* __restrict__ gamma, const float* __restrict__ beta,
    float* __restrict__ ab /*[a128, b128]*/) {
  int t = threadIdx.x;  // 128
  float mean = stats[t] / M;
  float var = stats[DIM + t] / M - mean * mean;
  float a = gamma[t] * rsqrtf(var + 1e-5f);
  ab[t] = a;
  ab[DIM + t] = beta[t] - mean * a;
}

// ---- fold BN affine (+scale) into weight; emit TRANSPOSED bf16 + fp32 bias ----
// WT[d][k] = bf16(scale * a[k] * W[k][d]);  bias[d] = scale * sum_k b[k]*W[k][d]
__global__ __launch_bounds__(128) void fold_weight_T_kernel(
    const float* __restrict__ W, const float* __restrict__ ab, float scale,
    short* __restrict__ WT, float* __restrict__ bias) {
  int d = threadIdx.x;  // 128
  float acc = 0.f;
  for (int k = 0; k < DIM; ++k) {
    float wv = W[k * DIM + d];
    WT[d * DIM + k] = f2bf(scale * ab[k] * wv);
    acc += ab[DIM + k] * wv;
  }
  bias[d] = scale * acc;
}

// ---- load A fragments (4 k-steps) for 16 rows starting at m0, fp32->bf16 ----
__device__ inline void load_a_frags(const float* __restrict__ X, long m0,
                                    int lr, int lg, bf16x8 a[4]) {
#pragma unroll
  for (int ks = 0; ks < 4; ++ks) {
    const float* p = X + (m0 + lr) * DIM + ks * 32 + lg * 8;
    float4 v0 = *reinterpret_cast<const float4*>(p);
    float4 v1 = *reinterpret_cast<const float4*>(p + 4);
    bf16x8 af;
    af[0] = f2bf(v0.x); af[1] = f2bf(v0.y); af[2] = f2bf(v0.z); af[3] = f2bf(v0.w);
    af[4] = f2bf(v1.x); af[5] = f2bf(v1.y); af[6] = f2bf(v1.z); af[7] = f2bf(v1.w);
    a[ks] = af;
  }
}

// ---------------- QKV via MFMA: 64 nodes per block, 4 waves ----------------
__global__ __launch_bounds__(256) void qkv_mfma_kernel(
    const float* __restrict__ nf,
    const short* __restrict__ WqT, const short* __restrict__ WkT, const short* __restrict__ WvT,
    const float* __restrict__ bq, const float* __restrict__ bk, const float* __restrict__ bv,
    float* __restrict__ Q, float* __restrict__ K, float* __restrict__ V) {
  int t = threadIdx.x;
  int w = t >> 6, l = t & 63;
  int lr = l & 15, lg = l >> 4;
  long m0 = (long)blockIdx.x * 64 + w * 16;
  if (m0 >= N_NODES) return;  // tail block (50000 % 64 != 0, % 16 == 0)
  bf16x8 a[4];
  load_a_frags(nf, m0, lr, lg, a);
  const short* Ws[3] = {WqT, WkT, WvT};
  const float* bs[3] = {bq, bk, bv};
  float* Os[3] = {Q, K, V};
#pragma unroll 1
  for (int m = 0; m < 3; ++m) {
    const short* WT = Ws[m];
    f32x4 acc[8];
#pragma unroll
    for (int ct = 0; ct < 8; ++ct) acc[ct] = (f32x4){0.f, 0.f, 0.f, 0.f};
#pragma unroll
    for (int ct = 0; ct < 8; ++ct) {
#pragma unroll
      for (int ks = 0; ks < 4; ++ks) {
        bf16x8 b = *reinterpret_cast<const bf16x8*>(WT + (ct * 16 + lr) * DIM + ks * 32 + lg * 8);
        acc[ct] = __builtin_amdgcn_mfma_f32_16x16x32_bf16(a[ks], b, acc[ct], 0, 0, 0);
      }
    }
    const float* bb = bs[m];
    float* O = Os[m];
#pragma unroll
    for (int ct = 0; ct < 8; ++ct) {
      float bcol = bb[ct * 16 + lr];
#pragma unroll
      for (int r = 0; r < 4; ++r) {
        O[(m0 + lg * 4 + r) * DIM + ct * 16 + lr] = acc[ct][r] + bcol;
      }
    }
  }
}

// ---------------- edge attention: 64 edges per block, MFMA projection ----------------
__global__ __launch_bounds__(256) void edge_mfma_kernel(
    const float* __restrict__ ef,
    const int* __restrict__ src, const int* __restrict__ dst,
    const short* __restrict__ WeT, const float* __restrict__ be,
    const float* __restrict__ Q, const float* __restrict__ K, const float* __restrict__ V,
    float* __restrict__ wV, float* __restrict__ z) {
  __shared__ float pe_lds[64][132];  // +4 pad: write groups land on disjoint bank halves
  __shared__ int s_src[64], s_dst[64];
  int t = threadIdx.x;
  int w = t >> 6, l = t & 63;
  int lr = l & 15, lg = l >> 4;
  long e0 = (long)blockIdx.x * 64;
  if (t < 64) { s_src[t] = src[e0 + t]; s_dst[t] = dst[e0 + t]; }

  // ---- phase 1: pe = BN(ef) @ We  (BN folded into WeT), 16 edges per wave ----
  long m0 = e0 + w * 16;
  bf16x8 a[4];
  load_a_frags(ef, m0, lr, lg, a);
  f32x4 acc[8];
#pragma unroll
  for (int ct = 0; ct < 8; ++ct) acc[ct] = (f32x4){0.f, 0.f, 0.f, 0.f};
#pragma unroll
  for (int ct = 0; ct < 8; ++ct) {
#pragma unroll
    for (int ks = 0; ks < 4; ++ks) {
      bf16x8 b = *reinterpret_cast<const bf16x8*>(WeT + (ct * 16 + lr) * DIM + ks * 32 + lg * 8);
      acc[ct] = __builtin_amdgcn_mfma_f32_16x16x32_bf16(a[ks], b, acc[ct], 0, 0, 0);
    }
  }
#pragma unroll
  for (int ct = 0; ct < 8; ++ct) {
    float bev = be[ct * 16 + lr];
#pragma unroll
    for (int r = 0; r < 4; ++r) {
      pe_lds[w * 16 + lg * 4 + r][ct * 16 + lr] = acc[ct][r] + bev;
    }
  }
  __syncthreads();

  // ---- phase 2: score + exp + scatter.  col c = t&127, 2 edges in parallel ----
  int c = t & 127;
  int sub = t >> 7;
  int h = c >> 5;
#pragma unroll 1
  for (int i = 0; i < 32; ++i) {
    int le = i * 2 + sub;
    int sn = s_src[le], dn = s_dst[le];
    float kv = K[(long)sn * DIM + c];  // 1/sqrt(32) pre-folded into K
    float qv = Q[(long)dn * DIM + c];
    float sc = kv * qv;
    sc = fminf(fmaxf(sc, -5.f), 5.f);
    sc *= pe_lds[le][c];
#pragma unroll
    for (int m2 = 16; m2 >= 1; m2 >>= 1) sc += __shfl_xor(sc, m2);
    float ssum = fminf(fmaxf(sc, -5.f), 5.f);
    float s = __expf(ssum);
    float vv = V[(long)sn * DIM + c];
    atomicAdd(&wV[(long)dn * DIM + c], s * vv);
    if ((l & 31) == 0) atomicAdd(&z[dn * NH + h], s);
  }
}

// ---------------- attention out: h = wV/z @ O_w + O_b + residual; BN2 stats ----------------
__global__ __launch_bounds__(128) void attnout_kernel(
    const float* __restrict__ wV, const float* __restrict__ z,
    const float* __restrict__ Ow, const float* __restrict__ Ob,
    const float* __restrict__ h_in1,
    float* __restrict__ hres, float* __restrict__ stats2) {
  __shared__ float rows[16][DIM];
  int t = threadIdx.x;  // 128
  int n0 = blockIdx.x * 16;
  for (int i = 0; i < 16; ++i) {
    int n = n0 + i;
    float zz = z[n * NH + (t >> 5)];
    rows[i][t] = wV[(long)n * DIM + t] / (zz + 1e-6f);
  }
  __syncthreads();
  float acc[16];
  float ob = Ob[t];
#pragma unroll
  for (int i = 0; i < 16; ++i) acc[i] = ob;
  for (int c4 = 0; c4 < 32; ++c4) {
    float w0 = Ow[(4 * c4 + 0) * DIM + t];
    float w1 = Ow[(4 * c4 + 1) * DIM + t];
    float w2 = Ow[(4 * c4 + 2) * DIM + t];
    float w3 = Ow[(4 * c4 + 3) * DIM + t];
#pragma unroll
    for (int i = 0; i < 16; ++i) {
      float4 r = *reinterpret_cast<const float4*>(&rows[i][4 * c4]);
      acc[i] += r.x * w0 + r.y * w1 + r.z * w2 + r.w * w3;
    }
  }
  float lsum = 0.f, lsq = 0.f;
  for (int i = 0; i < 16; ++i) {
    long idx = (long)(n0 + i) * DIM + t;
    float hv = h_in1[idx] + acc[i];
    hres[idx] = hv;
    lsum += hv; lsq += hv * hv;
  }
  atomicAdd(&stats2[t], lsum);
  atomicAdd(&stats2[DIM + t], lsq);
}

// ---------------- MLP: 8 nodes per block, 256 threads ----------------
__global__ __launch_bounds__(256) void mlp_kernel(
    const float* hres, const float* __restrict__ ab2,
    const float* __restrict__ W1, const float* __restrict__ W2,
    float* out) {
  __shared__ float rows[8][DIM];
  __shared__ float mid[8][2 * DIM];
  int t = threadIdx.x;  // 256
  int n0 = blockIdx.x * 8;
  {
    int c = t & 127;
    int half = t >> 7;
    float a = ab2[c], b = ab2[DIM + c];
    for (int i = half; i < 8; i += 2) {
      float hv = hres[(long)(n0 + i) * DIM + c];
      rows[i][c] = a * hv + b;
    }
  }
  __syncthreads();
  // phase 1: mid = silu(rows @ W1)  (W1: [128][256])
  float acc[8];
#pragma unroll
  for (int i = 0; i < 8; ++i) acc[i] = 0.f;
  for (int c4 = 0; c4 < 32; ++c4) {
    float w0 = W1[(4 * c4 + 0) * 2 * DIM + t];
    float w1 = W1[(4 * c4 + 1) * 2 * DIM + t];
    float w2 = W1[(4 * c4 + 2) * 2 * DIM + t];
    float w3 = W1[(4 * c4 + 3) * 2 * DIM + t];
#pragma unroll
    for (int i = 0; i < 8; ++i) {
      float4 r = *reinterpret_cast<const float4*>(&rows[i][4 * c4]);
      acc[i] += r.x * w0 + r.y * w1 + r.z * w2 + r.w * w3;
    }
  }
#pragma unroll
  for (int i = 0; i < 8; ++i) {
    float x = acc[i];
    mid[i][t] = x / (1.f + __expf(-x));
  }
  __syncthreads();
  // phase 2: out = hres + mid @ W2  (W2: [256][128])
  int d = t & 127;
  int half = t >> 7;
  float acc2[4];
#pragma unroll
  for (int j = 0; j < 4; ++j) acc2[j] = 0.f;
  for (int k4 = 0; k4 < 64; ++k4) {
    float w0 = W2[(4 * k4 + 0) * DIM + d];
    float w1 = W2[(4 * k4 + 1) * DIM + d];
    float w2 = W2[(4 * k4 + 2) * DIM + d];
    float w3 = W2[(4 * k4 + 3) * DIM + d];
#pragma unroll
    for (int j = 0; j < 4; ++j) {
      float4 mv = *reinterpret_cast<const float4*>(&mid[half + j * 2][4 * k4]);
      acc2[j] += mv.x * w0 + mv.y * w1 + mv.z * w2 + mv.w * w3;
    }
  }
#pragma unroll
  for (int j = 0; j < 4; ++j) {
    int i = half + j * 2;
    long idx = (long)(n0 + i) * DIM + d;
    out[idx] = hres[idx] + acc2[j];
  }
}

extern "C" void kernel_launch(void* const* d_in, const int* in_sizes, int n_in,
                              void* d_out, int out_size, void* d_ws, size_t ws_size,
                              hipStream_t stream) {
  const float* node_feats = (const float*)d_in[0];
  const float* edge_feats = (const float*)d_in[1];
  const int* src = (const int*)d_in[2];
  const int* dst = (const int*)d_in[3];
  const float* Wq = (const float*)d_in[4];
  const float* Wk = (const float*)d_in[5];
  const float* Wv = (const float*)d_in[6];
  const float* We = (const float*)d_in[7];
  const float* Ow = (const float*)d_in[8];
  const float* Ob = (const float*)d_in[9];
  const float* g1n = (const float*)d_in[10];
  const float* b1n = (const float*)d_in[11];
  const float* g1e = (const float*)d_in[12];
  const float* b1e = (const float*)d_in[13];
  const float* g2 = (const float*)d_in[14];
  const float* b2 = (const float*)d_in[15];
  const float* W1 = (const float*)d_in[16];
  const float* W2 = (const float*)d_in[17];
  float* out = (float*)d_out;
  float* w = (float*)d_ws;

  float* stats_n = w + 0;
  float* stats_e = w + 256;
  float* stats_h = w + 512;
  float* ab_n = w + 768;
  float* ab_e = w + 1024;
  float* ab_2 = w + 1280;
  float* bq = w + 1536;
  float* bk = w + 1664;
  float* bv = w + 1792;
  float* be = w + 1920;
  short* WqT = (short*)(w + 2048);   // 16384 shorts = 8192 floats
  short* WkT = (short*)(w + 10240);
  short* WvT = (short*)(w + 18432);
  short* WeT = (short*)(w + 26624);
  float* Q = w + 34816;
  float* K = Q + (size_t)N_NODES * DIM;
  float* V = K + (size_t)N_NODES * DIM;
  float* wV = V + (size_t)N_NODES * DIM;
  float* z = wV + (size_t)N_NODES * DIM;

  const float inv_s = 0.17677669529663687f;  // 1/sqrt(32), folded into K

  // zero the accumulators (stats + scatter targets)
  hipMemsetAsync(w, 0, 768 * sizeof(float), stream);
  hipMemsetAsync(wV, 0, (size_t)(N_NODES * DIM + N_NODES * NH) * sizeof(float), stream);

  bn_stats_kernel<<<512, 256, 0, stream>>>(node_feats, N_NODES, stats_n);
  bn_stats_kernel<<<2048, 256, 0, stream>>>(edge_feats, N_EDGES, stats_e);
  finalize_ab_kernel<<<1, 128, 0, stream>>>(stats_n, (float)N_NODES, g1n, b1n, ab_n);
  finalize_ab_kernel<<<1, 128, 0, stream>>>(stats_e, (float)N_EDGES, g1e, b1e, ab_e);
  fold_weight_T_kernel<<<1, 128, 0, stream>>>(Wq, ab_n, 1.0f, WqT, bq);
  fold_weight_T_kernel<<<1, 128, 0, stream>>>(Wk, ab_n, inv_s, WkT, bk);
  fold_weight_T_kernel<<<1, 128, 0, stream>>>(Wv, ab_n, 1.0f, WvT, bv);
  fold_weight_T_kernel<<<1, 128, 0, stream>>>(We, ab_e, 1.0f, WeT, be);
  qkv_mfma_kernel<<<(N_NODES + 63) / 64, 256, 0, stream>>>(
      node_feats, WqT, WkT, WvT, bq, bk, bv, Q, K, V);
  edge_mfma_kernel<<<N_EDGES / 64, 256, 0, stream>>>(
      edge_feats, src, dst, WeT, be, Q, K, V, wV, z);
  attnout_kernel<<<N_NODES / 16, 128, 0, stream>>>(wV, z, Ow, Ob, node_feats, out, stats_h);
  finalize_ab_kernel<<<1, 128, 0, stream>>>(stats_h, (float)N_NODES, g2, b2, ab_2);
  mlp_kernel<<<N_NODES / 8, 256, 0, stream>>>(out, ab_2, W1, W2, out);
}

// Round 3
// 1053.123 us; speedup vs baseline: 1.2993x; 1.1092x over previous
//
#include <hip/hip_runtime.h>
#include <hip/hip_bf16.h>
#include <math.h>

#define N_NODES 50000
#define N_EDGES 800000
#define DIM 128
#define NH 4

typedef __attribute__((ext_vector_type(8))) short bf16x8;
typedef __attribute__((ext_vector_type(4))) float f32x4;

__device__ inline short f2bf(float f) {
  __hip_bfloat16 h = __float2bfloat16(f);
  return __builtin_bit_cast(short, h);
}

// ---------------- BN stats: per-column sum & sumsq ----------------
__global__ __launch_bounds__(256) void bn_stats_kernel(
    const float* __restrict__ x, int M, float* __restrict__ out /*[sum128, sq128]*/) {
  __shared__ float s_sum[DIM];
  __shared__ float s_sq[DIM];
  int t = threadIdx.x;  // 256
  if (t < DIM) { s_sum[t] = 0.f; s_sq[t] = 0.f; }
  __syncthreads();
  int c4 = (t & 31) * 4;   // column group (float4)
  int rg = t >> 5;         // row sub-group: 8 rows per iteration
  float sum0=0,sum1=0,sum2=0,sum3=0, sq0=0,sq1=0,sq2=0,sq3=0;
  for (long row = (long)blockIdx.x * 8 + rg; row < M; row += (long)gridDim.x * 8) {
    float4 v = *reinterpret_cast<const float4*>(x + row * DIM + c4);
    sum0 += v.x; sq0 += v.x * v.x;
    sum1 += v.y; sq1 += v.y * v.y;
    sum2 += v.z; sq2 += v.z * v.z;
    sum3 += v.w; sq3 += v.w * v.w;
  }
  atomicAdd(&s_sum[c4 + 0], sum0); atomicAdd(&s_sq[c4 + 0], sq0);
  atomicAdd(&s_sum[c4 + 1], sum1); atomicAdd(&s_sq[c4 + 1], sq1);
  atomicAdd(&s_sum[c4 + 2], sum2); atomicAdd(&s_sq[c4 + 2], sq2);
  atomicAdd(&s_sum[c4 + 3], sum3); atomicAdd(&s_sq[c4 + 3], sq3);
  __syncthreads();
  if (t < DIM) {
    atomicAdd(&out[t], s_sum[t]);
    atomicAdd(&out[DIM + t], s_sq[t]);
  }
}

// ---------------- finalize affine a,b from stats ----------------
__global__ __launch_bounds__(128) void finalize_ab_kernel(
    const float* __restrict__ stats, float M,
    const float* __restrict__ gamma, const float* __restrict__ beta,
    float* __restrict__ ab /*[a128, b128]*/) {
  int t = threadIdx.x;  // 128
  float mean = stats[t] / M;
  float var = stats[DIM + t] / M - mean * mean;
  float a = gamma[t] * rsqrtf(var + 1e-5f);
  ab[t] = a;
  ab[DIM + t] = beta[t] - mean * a;
}

// ---- fold BN affine (+scale) into weight; emit TRANSPOSED bf16 + fp32 bias ----
__global__ __launch_bounds__(128) void fold_weight_T_kernel(
    const float* __restrict__ W, const float* __restrict__ ab, float scale,
    short* __restrict__ WT, float* __restrict__ bias) {
  int d = threadIdx.x;  // 128
  float acc = 0.f;
  for (int k = 0; k < DIM; ++k) {
    float wv = W[k * DIM + d];
    WT[d * DIM + k] = f2bf(scale * ab[k] * wv);
    acc += ab[DIM + k] * wv;
  }
  bias[d] = scale * acc;
}

// ---- load A fragments (4 k-steps) for 16 rows starting at m0, fp32->bf16 ----
__device__ inline void load_a_frags(const float* __restrict__ X, long m0,
                                    int lr, int lg, bf16x8 a[4]) {
#pragma unroll
  for (int ks = 0; ks < 4; ++ks) {
    const float* p = X + (m0 + lr) * DIM + ks * 32 + lg * 8;
    float4 v0 = *reinterpret_cast<const float4*>(p);
    float4 v1 = *reinterpret_cast<const float4*>(p + 4);
    bf16x8 af;
    af[0] = f2bf(v0.x); af[1] = f2bf(v0.y); af[2] = f2bf(v0.z); af[3] = f2bf(v0.w);
    af[4] = f2bf(v1.x); af[5] = f2bf(v1.y); af[6] = f2bf(v1.z); af[7] = f2bf(v1.w);
    a[ks] = af;
  }
}

// ---------------- QKV via MFMA: 64 nodes per block, 4 waves ----------------
__global__ __launch_bounds__(256) void qkv_mfma_kernel(
    const float* __restrict__ nf,
    const short* __restrict__ WqT, const short* __restrict__ WkT, const short* __restrict__ WvT,
    const float* __restrict__ bq, const float* __restrict__ bk, const float* __restrict__ bv,
    float* __restrict__ Q, float* __restrict__ K, float* __restrict__ V) {
  int t = threadIdx.x;
  int w = t >> 6, l = t & 63;
  int lr = l & 15, lg = l >> 4;
  long m0 = (long)blockIdx.x * 64 + w * 16;
  if (m0 >= N_NODES) return;  // tail waves (50000 % 64 != 0, % 16 == 0)
  bf16x8 a[4];
  load_a_frags(nf, m0, lr, lg, a);
  const short* Ws[3] = {WqT, WkT, WvT};
  const float* bs[3] = {bq, bk, bv};
  float* Os[3] = {Q, K, V};
#pragma unroll 1
  for (int m = 0; m < 3; ++m) {
    const short* WT = Ws[m];
    f32x4 acc[8];
#pragma unroll
    for (int ct = 0; ct < 8; ++ct) acc[ct] = (f32x4){0.f, 0.f, 0.f, 0.f};
#pragma unroll
    for (int ct = 0; ct < 8; ++ct) {
#pragma unroll
      for (int ks = 0; ks < 4; ++ks) {
        bf16x8 b = *reinterpret_cast<const bf16x8*>(WT + (ct * 16 + lr) * DIM + ks * 32 + lg * 8);
        acc[ct] = __builtin_amdgcn_mfma_f32_16x16x32_bf16(a[ks], b, acc[ct], 0, 0, 0);
      }
    }
    const float* bb = bs[m];
    float* O = Os[m];
#pragma unroll
    for (int ct = 0; ct < 8; ++ct) {
      float bcol = bb[ct * 16 + lr];
#pragma unroll
      for (int r = 0; r < 4; ++r) {
        O[(m0 + lg * 4 + r) * DIM + ct * 16 + lr] = acc[ct][r] + bcol;
      }
    }
  }
}

// ---------------- CSR build ----------------
__global__ __launch_bounds__(256) void hist_kernel(
    const int* __restrict__ dst, int* __restrict__ deg) {
  int i = blockIdx.x * 256 + threadIdx.x;  // exact grid: E/256
  atomicAdd(&deg[dst[i]], 1);
}

#define SCAN_T 1024
#define PER_T 49  // ceil(50000/1024)
__global__ __launch_bounds__(SCAN_T) void scan_kernel(
    const int* __restrict__ deg, int* __restrict__ row_start, int* __restrict__ cursor) {
  __shared__ int ps[SCAN_T];
  int t = threadIdx.x;
  int base = t * PER_T;
  int lsum = 0;
  int local[PER_T];
#pragma unroll
  for (int j = 0; j < PER_T; ++j) {
    int idx = base + j;
    int d = (idx < N_NODES) ? deg[idx] : 0;
    local[j] = lsum;
    lsum += d;
  }
  ps[t] = lsum;
  __syncthreads();
  for (int off = 1; off < SCAN_T; off <<= 1) {
    int v = (t >= off) ? ps[t - off] : 0;
    __syncthreads();
    ps[t] += v;
    __syncthreads();
  }
  int prefix = (t == 0) ? 0 : ps[t - 1];
#pragma unroll
  for (int j = 0; j < PER_T; ++j) {
    int idx = base + j;
    if (idx < N_NODES) {
      int v = prefix + local[j];
      row_start[idx] = v;
      cursor[idx] = v;
    }
  }
  if (t == SCAN_T - 1) row_start[N_NODES] = ps[SCAN_T - 1];
}

__global__ __launch_bounds__(256) void scatter_kernel(
    const int* __restrict__ src, const int* __restrict__ dst,
    int* __restrict__ cursor, int2* __restrict__ csr) {
  int i = blockIdx.x * 256 + threadIdx.x;  // exact grid: E/256
  int d = dst[i];
  int pos = atomicAdd(&cursor[d], 1);
  csr[pos] = make_int2(src[i], i);
}

// ------- edge score: MFMA proj + in-register per-head score, no LDS, no atomics -------
__global__ __launch_bounds__(256) void edge_score_kernel(
    const float* __restrict__ ef,
    const int* __restrict__ src, const int* __restrict__ dst,
    const short* __restrict__ WeT, const float* __restrict__ be,
    const float* __restrict__ Q, const float* __restrict__ K,
    float* __restrict__ s_out) {
  int t = threadIdx.x;
  int w = t >> 6, l = t & 63;
  int lr = l & 15, lg = l >> 4;
  long m0 = (long)blockIdx.x * 64 + w * 16;

  bf16x8 a[4];
  load_a_frags(ef, m0, lr, lg, a);
  float ber[8];
#pragma unroll
  for (int ct = 0; ct < 8; ++ct) ber[ct] = be[ct * 16 + lr];

  f32x4 acc[8];
#pragma unroll
  for (int ct = 0; ct < 8; ++ct) acc[ct] = (f32x4){0.f, 0.f, 0.f, 0.f};
#pragma unroll
  for (int ct = 0; ct < 8; ++ct) {
#pragma unroll
    for (int ks = 0; ks < 4; ++ks) {
      bf16x8 b = *reinterpret_cast<const bf16x8*>(WeT + (ct * 16 + lr) * DIM + ks * 32 + lg * 8);
      acc[ct] = __builtin_amdgcn_mfma_f32_16x16x32_bf16(a[ks], b, acc[ct], 0, 0, 0);
    }
  }

  // acc[ct][r] = pe for edge row (lg*4+r), col (ct*16+lr).  head(col) = ct>>1.
#pragma unroll
  for (int r = 0; r < 4; ++r) {
    long e = m0 + lg * 4 + r;
    int sn = src[e];
    int dn = dst[e];
    float hs0 = 0.f, hs1 = 0.f, hs2 = 0.f, hs3 = 0.f;
#pragma unroll
    for (int ct = 0; ct < 8; ++ct) {
      int c = ct * 16 + lr;
      float kv = K[(long)sn * DIM + c];  // 1/sqrt(32) pre-folded into K
      float qv = Q[(long)dn * DIM + c];
      float sc = fminf(fmaxf(kv * qv, -5.f), 5.f) * (acc[ct][r] + ber[ct]);
      if (ct < 2) hs0 += sc; else if (ct < 4) hs1 += sc; else if (ct < 6) hs2 += sc; else hs3 += sc;
    }
    // reduce over the 16 lr-lanes (xor masks 1,2,4,8 stay within lg group)
#pragma unroll
    for (int m2 = 8; m2 >= 1; m2 >>= 1) {
      hs0 += __shfl_xor(hs0, m2);
      hs1 += __shfl_xor(hs1, m2);
      hs2 += __shfl_xor(hs2, m2);
      hs3 += __shfl_xor(hs3, m2);
    }
    float myh = (lr == 0) ? hs0 : ((lr == 1) ? hs1 : ((lr == 2) ? hs2 : hs3));
    if (lr < 4) s_out[e * 4 + lr] = __expf(fminf(fmaxf(myh, -5.f), 5.f));
  }
}

// ------- aggregate: one wave per dst node over its CSR row; no atomics -------
__global__ __launch_bounds__(256) void aggregate_kernel(
    const int* __restrict__ row_start, const int2* __restrict__ csr,
    const float* __restrict__ s_arr, const float* __restrict__ V,
    float* __restrict__ hagg) {
  int t = threadIdx.x;
  int w = t >> 6, l = t & 63;
  int n = blockIdx.x * 4 + w;  // exact grid: N/4
  int r0 = row_start[n], r1 = row_start[n + 1];
  int h = l >> 4;
  float a0 = 0.f, a1 = 0.f, zacc = 0.f;
  for (int idx = r0; idx < r1; ++idx) {
    int2 rec = csr[idx];
    float sh = s_arr[(long)rec.y * 4 + h];
    float2 v = *reinterpret_cast<const float2*>(V + (long)rec.x * DIM + l * 2);
    a0 += sh * v.x; a1 += sh * v.y; zacc += sh;
  }
  float inv = 1.f / (zacc + 1e-6f);
  float2 o; o.x = a0 * inv; o.y = a1 * inv;
  *reinterpret_cast<float2*>(hagg + (long)n * DIM + l * 2) = o;
}

// ---------------- attention out: h = hagg @ O_w + O_b + residual; BN2 stats ----------------
__global__ __launch_bounds__(128) void attnout_kernel(
    const float* __restrict__ hagg,
    const float* __restrict__ Ow, const float* __restrict__ Ob,
    const float* __restrict__ h_in1,
    float* __restrict__ hres, float* __restrict__ stats2) {
  __shared__ float rows[16][DIM];
  int t = threadIdx.x;  // 128
  int n0 = blockIdx.x * 16;
  for (int i = 0; i < 16; ++i) {
    rows[i][t] = hagg[(long)(n0 + i) * DIM + t];
  }
  __syncthreads();
  float acc[16];
  float ob = Ob[t];
#pragma unroll
  for (int i = 0; i < 16; ++i) acc[i] = ob;
  for (int c4 = 0; c4 < 32; ++c4) {
    float w0 = Ow[(4 * c4 + 0) * DIM + t];
    float w1 = Ow[(4 * c4 + 1) * DIM + t];
    float w2 = Ow[(4 * c4 + 2) * DIM + t];
    float w3 = Ow[(4 * c4 + 3) * DIM + t];
#pragma unroll
    for (int i = 0; i < 16; ++i) {
      float4 r = *reinterpret_cast<const float4*>(&rows[i][4 * c4]);
      acc[i] += r.x * w0 + r.y * w1 + r.z * w2 + r.w * w3;
    }
  }
  float lsum = 0.f, lsq = 0.f;
  for (int i = 0; i < 16; ++i) {
    long idx = (long)(n0 + i) * DIM + t;
    float hv = h_in1[idx] + acc[i];
    hres[idx] = hv;
    lsum += hv; lsq += hv * hv;
  }
  atomicAdd(&stats2[t], lsum);
  atomicAdd(&stats2[DIM + t], lsq);
}

// ---------------- MLP: 8 nodes per block, 256 threads ----------------
__global__ __launch_bounds__(256) void mlp_kernel(
    const float* hres, const float* __restrict__ ab2,
    const float* __restrict__ W1, const float* __restrict__ W2,
    float* out) {
  __shared__ float rows[8][DIM];
  __shared__ float mid[8][2 * DIM];
  int t = threadIdx.x;  // 256
  int n0 = blockIdx.x * 8;
  {
    int c = t & 127;
    int half = t >> 7;
    float a = ab2[c], b = ab2[DIM + c];
    for (int i = half; i < 8; i += 2) {
      float hv = hres[(long)(n0 + i) * DIM + c];
      rows[i][c] = a * hv + b;
    }
  }
  __syncthreads();
  float acc[8];
#pragma unroll
  for (int i = 0; i < 8; ++i) acc[i] = 0.f;
  for (int c4 = 0; c4 < 32; ++c4) {
    float w0 = W1[(4 * c4 + 0) * 2 * DIM + t];
    float w1 = W1[(4 * c4 + 1) * 2 * DIM + t];
    float w2 = W1[(4 * c4 + 2) * 2 * DIM + t];
    float w3 = W1[(4 * c4 + 3) * 2 * DIM + t];
#pragma unroll
    for (int i = 0; i < 8; ++i) {
      float4 r = *reinterpret_cast<const float4*>(&rows[i][4 * c4]);
      acc[i] += r.x * w0 + r.y * w1 + r.z * w2 + r.w * w3;
    }
  }
#pragma unroll
  for (int i = 0; i < 8; ++i) {
    float x = acc[i];
    mid[i][t] = x / (1.f + __expf(-x));
  }
  __syncthreads();
  int d = t & 127;
  int half = t >> 7;
  float acc2[4];
#pragma unroll
  for (int j = 0; j < 4; ++j) acc2[j] = 0.f;
  for (int k4 = 0; k4 < 64; ++k4) {
    float w0 = W2[(4 * k4 + 0) * DIM + d];
    float w1 = W2[(4 * k4 + 1) * DIM + d];
    float w2 = W2[(4 * k4 + 2) * DIM + d];
    float w3 = W2[(4 * k4 + 3) * DIM + d];
#pragma unroll
    for (int j = 0; j < 4; ++j) {
      float4 mv = *reinterpret_cast<const float4*>(&mid[half + j * 2][4 * k4]);
      acc2[j] += mv.x * w0 + mv.y * w1 + mv.z * w2 + mv.w * w3;
    }
  }
#pragma unroll
  for (int j = 0; j < 4; ++j) {
    int i = half + j * 2;
    long idx = (long)(n0 + i) * DIM + d;
    out[idx] = hres[idx] + acc2[j];
  }
}

extern "C" void kernel_launch(void* const* d_in, const int* in_sizes, int n_in,
                              void* d_out, int out_size, void* d_ws, size_t ws_size,
                              hipStream_t stream) {
  const float* node_feats = (const float*)d_in[0];
  const float* edge_feats = (const float*)d_in[1];
  const int* src = (const int*)d_in[2];
  const int* dst = (const int*)d_in[3];
  const float* Wq = (const float*)d_in[4];
  const float* Wk = (const float*)d_in[5];
  const float* Wv = (const float*)d_in[6];
  const float* We = (const float*)d_in[7];
  const float* Ow = (const float*)d_in[8];
  const float* Ob = (const float*)d_in[9];
  const float* g1n = (const float*)d_in[10];
  const float* b1n = (const float*)d_in[11];
  const float* g1e = (const float*)d_in[12];
  const float* b1e = (const float*)d_in[13];
  const float* g2 = (const float*)d_in[14];
  const float* b2 = (const float*)d_in[15];
  const float* W1 = (const float*)d_in[16];
  const float* W2 = (const float*)d_in[17];
  float* out = (float*)d_out;
  float* w = (float*)d_ws;

  float* stats_n = w + 0;
  float* stats_e = w + 256;
  float* stats_h = w + 512;
  float* ab_n = w + 768;
  float* ab_e = w + 1024;
  float* ab_2 = w + 1280;
  float* bq = w + 1536;
  float* bk = w + 1664;
  float* bv = w + 1792;
  float* be = w + 1920;
  short* WqT = (short*)(w + 2048);   // 16384 shorts = 8192 floats each
  short* WkT = (short*)(w + 10240);
  short* WvT = (short*)(w + 18432);
  short* WeT = (short*)(w + 26624);
  float* Q = w + 34816;
  float* K = Q + (size_t)N_NODES * DIM;
  float* V = K + (size_t)N_NODES * DIM;
  float* s_arr = V + (size_t)N_NODES * DIM;          // E*4 floats
  int* deg = (int*)(s_arr + (size_t)N_EDGES * 4);    // 50000 ints
  int* row_start = deg + 50048;                      // 50001 ints (padded)
  int* cursor = row_start + 50064;
  int2* csr = (int2*)(cursor + 50048);               // E int2 (8B-aligned)
  float* hagg = Q;  // Q is dead after edge_score; reuse for aggregated output

  const float inv_s = 0.17677669529663687f;  // 1/sqrt(32), folded into K

  hipMemsetAsync(w, 0, 768 * sizeof(float), stream);
  hipMemsetAsync(deg, 0, 50000 * sizeof(int), stream);

  bn_stats_kernel<<<512, 256, 0, stream>>>(node_feats, N_NODES, stats_n);
  bn_stats_kernel<<<2048, 256, 0, stream>>>(edge_feats, N_EDGES, stats_e);
  finalize_ab_kernel<<<1, 128, 0, stream>>>(stats_n, (float)N_NODES, g1n, b1n, ab_n);
  finalize_ab_kernel<<<1, 128, 0, stream>>>(stats_e, (float)N_EDGES, g1e, b1e, ab_e);
  fold_weight_T_kernel<<<1, 128, 0, stream>>>(Wq, ab_n, 1.0f, WqT, bq);
  fold_weight_T_kernel<<<1, 128, 0, stream>>>(Wk, ab_n, inv_s, WkT, bk);
  fold_weight_T_kernel<<<1, 128, 0, stream>>>(Wv, ab_n, 1.0f, WvT, bv);
  fold_weight_T_kernel<<<1, 128, 0, stream>>>(We, ab_e, 1.0f, WeT, be);

  hist_kernel<<<N_EDGES / 256, 256, 0, stream>>>(dst, deg);
  scan_kernel<<<1, SCAN_T, 0, stream>>>(deg, row_start, cursor);
  scatter_kernel<<<N_EDGES / 256, 256, 0, stream>>>(src, dst, cursor, csr);

  qkv_mfma_kernel<<<(N_NODES + 63) / 64, 256, 0, stream>>>(
      node_feats, WqT, WkT, WvT, bq, bk, bv, Q, K, V);
  edge_score_kernel<<<N_EDGES / 64, 256, 0, stream>>>(
      edge_feats, src, dst, WeT, be, Q, K, s_arr);
  aggregate_kernel<<<N_NODES / 4, 256, 0, stream>>>(row_start, csr, s_arr, V, hagg);
  attnout_kernel<<<N_NODES / 16, 128, 0, stream>>>(hagg, Ow, Ob, node_feats, out, stats_h);
  finalize_ab_kernel<<<1, 128, 0, stream>>>(stats_h, (float)N_NODES, g2, b2, ab_2);
  mlp_kernel<<<N_NODES / 8, 256, 0, stream>>>(out, ab_2, W1, W2, out);
}